// Round 13
// baseline (404.040 us; speedup 1.0000x reference)
//
#include <hip/hip_runtime.h>
#include <hip/hip_bf16.h>

typedef __attribute__((ext_vector_type(8))) short short8;
typedef __attribute__((ext_vector_type(4))) float f32x4;
typedef __attribute__((ext_vector_type(2))) float f32x2;
typedef unsigned short u16;
typedef unsigned int u32;
typedef unsigned char u8;
typedef unsigned long long u64;
typedef long long i64;

#define NORM_INV (1.0f / 100.0f)

__device__ __forceinline__ float silu(float x) {
    return x * __builtin_amdgcn_rcpf(1.0f + __expf(-x));
}

__device__ __forceinline__ u16 f2bf(float x) {
    union { float f; u32 u; } v; v.f = x;
    u32 r = v.u + 0x7fff + ((v.u >> 16) & 1);   // RNE
    return (u16)(r >> 16);
}

// ---------------- kernel 0: weight transposes (tiny) ----------------
__global__ void prep_weights(const float* __restrict__ W1, const float* __restrict__ W2,
                             u16* __restrict__ W1abT, u8* __restrict__ W2T8) {
    int idx = blockIdx.x * blockDim.x + threadIdx.x;
    if (idx < 256 * 128) {
        int j = idx >> 7, k = idx & 127;
        float v = (j < 128) ? W1[k * 128 + j] : W1[(128 + k) * 128 + (j - 128)];
        W1abT[j * 128 + k] = f2bf(v);
    } else if (idx < 256 * 128 + 128 * 128) {
        int t = idx - 256 * 128;
        int n = t >> 7, k = t & 127;
        float v = W2[k * 128 + n];
        int pk = __builtin_amdgcn_cvt_pk_fp8_f32(v, v, 0, false);
        W2T8[n * 128 + k] = (u8)pk;
    }
}

// ---------------- kernel 1: AB8[node][256] = fp8[h@W1a + b1 | h@W1b] ----------------
__global__ __launch_bounds__(256) void ab_kernel(const float* __restrict__ h,
        const float* __restrict__ b1, const u16* __restrict__ W1abT,
        u8* __restrict__ AB8, int N) {
    __shared__ u16 hs[32 * 128];     // 32 nodes x 128 k, bf16, XOR-swizzled
    int tid = threadIdx.x;
    int n0 = blockIdx.x * 32;
    int lane = tid & 63, wave = tid >> 6;

    #pragma unroll
    for (int it = 0; it < 8; ++it) {
        int item = it * 256 + tid;          // 2048 items, 2 k each
        int m = item >> 6;
        int k = (item & 63) * 2;
        float2 hv = make_float2(0.f, 0.f);
        if (n0 + m < N) hv = *(const float2*)(h + (size_t)(n0 + m) * 128 + k);
        u32 pk = (u32)f2bf(hv.x) | ((u32)f2bf(hv.y) << 16);
        int byteoff = m * 256 + ((k * 2) ^ ((m & 7) << 4));
        *(u32*)((char*)hs + byteoff) = pk;
    }

    short8 bw[4][4];
    #pragma unroll
    for (int nt = 0; nt < 4; ++nt) {
        int j = wave * 64 + nt * 16 + (lane & 15);
        #pragma unroll
        for (int ks = 0; ks < 4; ++ks)
            bw[nt][ks] = *(const short8*)((const char*)W1abT + j * 256 + ks * 64 + (lane >> 4) * 16);
    }
    __syncthreads();

    f32x4 acc[2][4] = {};
    #pragma unroll
    for (int ks = 0; ks < 4; ++ks) {
        short8 a[2];
        #pragma unroll
        for (int mt = 0; mt < 2; ++mt) {
            int row = mt * 16 + (lane & 15);
            int byteoff = row * 256 + (((ks * 64) + ((lane >> 4) * 16)) ^ ((row & 7) << 4));
            a[mt] = *(short8*)((char*)hs + byteoff);
        }
        #pragma unroll
        for (int mt = 0; mt < 2; ++mt)
            #pragma unroll
            for (int nt = 0; nt < 4; ++nt)
                acc[mt][nt] = __builtin_amdgcn_mfma_f32_16x16x32_bf16(a[mt], bw[nt][ks], acc[mt][nt], 0, 0, 0);
    }

    #pragma unroll
    for (int mt = 0; mt < 2; ++mt) {
        #pragma unroll
        for (int nt = 0; nt < 4; ++nt) {
            int j = wave * 64 + nt * 16 + (lane & 15);
            float bias = (j < 128) ? b1[j] : 0.f;
            #pragma unroll
            for (int r = 0; r < 4; ++r) {
                int node = n0 + mt * 16 + (lane >> 4) * 4 + r;
                if (node < N) {
                    float v = acc[mt][nt][r] + bias;
                    int pk = __builtin_amdgcn_cvt_pk_fp8_f32(v, v, 0, false);
                    AB8[(size_t)node * 256 + j] = (u8)pk;
                }
            }
        }
    }
}

// fp8 gather pair + layer-1 finish + silu -> fp8 A-fragment
__device__ __forceinline__ i64 conv_frag(uint2 va, uint2 vb, float eac, int ks, int lg,
                                         volatile const float* vw1c) {
    f32x2 fa[4], fb[4];
    fa[0] = __builtin_amdgcn_cvt_pk_f32_fp8(va.x, false);
    fa[1] = __builtin_amdgcn_cvt_pk_f32_fp8(va.x, true);
    fa[2] = __builtin_amdgcn_cvt_pk_f32_fp8(va.y, false);
    fa[3] = __builtin_amdgcn_cvt_pk_f32_fp8(va.y, true);
    fb[0] = __builtin_amdgcn_cvt_pk_f32_fp8(vb.x, false);
    fb[1] = __builtin_amdgcn_cvt_pk_f32_fp8(vb.x, true);
    fb[2] = __builtin_amdgcn_cvt_pk_f32_fp8(vb.y, false);
    fb[3] = __builtin_amdgcn_cvt_pk_f32_fp8(vb.y, true);
    float x[8];
    #pragma unroll
    for (int jp = 0; jp < 4; ++jp) {
        float wcx = vw1c[ks * 32 + lg * 8 + 2 * jp];
        float wcy = vw1c[ks * 32 + lg * 8 + 2 * jp + 1];
        x[2 * jp]     = silu(fa[jp].x + fb[jp].x + eac * wcx);
        x[2 * jp + 1] = silu(fa[jp].y + fb[jp].y + eac * wcy);
    }
    u32 lo = 0, hi = 0;
    lo = __builtin_amdgcn_cvt_pk_fp8_f32(x[0], x[1], lo, false);
    lo = __builtin_amdgcn_cvt_pk_fp8_f32(x[2], x[3], lo, true);
    hi = __builtin_amdgcn_cvt_pk_fp8_f32(x[4], x[5], hi, false);
    hi = __builtin_amdgcn_cvt_pk_fp8_f32(x[6], x[7], hi, true);
    union { uint2 u; i64 l; } c; c.u = make_uint2(lo, hi);
    return c.l;
}

// Shared body for the real kernel (GATHER=1) and the deletion-ablation probe
// (GATHER=0: AB8 loads replaced by integer synthesis; everything else identical;
// rowc/colc remain consumed so no upstream DCE — rule #17).
template <int GATHER>
__device__ __forceinline__ void edge_body(
        const u8* __restrict__ AB8, const u8* __restrict__ W2T8,
        const int* __restrict__ eidx, const float* __restrict__ coord_diff,
        const float* __restrict__ edge_attr, const float* __restrict__ edge_mask,
        const float* __restrict__ W1, const float* __restrict__ b2,
        const float* __restrict__ W3, float* __restrict__ agg, int E) {
    __shared__ u8 w2s8[128 * 128];   // swizzled fp8 W2T copy (16 KB)
    __shared__ float ssc[4][2][16];  // per-wave, per-subtile scale scratch
    __shared__ float sw1c[128];
    __shared__ float sb2[128];
    __shared__ float sw3[128];

    const int tid = threadIdx.x;
    const int lane = tid & 63;
    const int wv = tid >> 6;
    const int le = lane & 15;
    const int lg = lane >> 4;

    #pragma unroll
    for (int it = 0; it < 8; ++it) {
        int idx = it * 256 + tid;
        int row = idx >> 4, c8 = idx & 15;
        u64 v = *(const u64*)(W2T8 + row * 128 + c8 * 8);
        *(u64*)(w2s8 + row * 128 + ((c8 * 8) ^ ((row & 7) << 4))) = v;
    }
    if (tid < 128) {
        sw1c[tid] = W1[256 * 128 + tid];
        sb2[tid]  = b2[tid];
        sw3[tid]  = W3[tid];
    }
    __syncthreads();

    volatile const float* vw1c = sw1c;
    volatile const float* vb2  = sb2;
    volatile const float* vw3  = sw3;

    const int ntiles = (E + 31) >> 5;
    const int wpb = blockDim.x >> 6;
    const int nwaves = gridDim.x * wpb;
    int tile = blockIdx.x * wpb + wv;
    if (tile >= ntiles) return;

    int e0 = tile << 5;
    int rowc[2], colc[2];
    float eac[2];
    #pragma unroll
    for (int st = 0; st < 2; ++st) {
        int ep = min(e0 + st * 16 + le, E - 1);
        rowc[st] = eidx[ep]; colc[st] = eidx[E + ep]; eac[st] = edge_attr[ep];
    }

    while (true) {
        uint2 va[2][4], vb[2][4];
        if (GATHER) {
            #pragma unroll
            for (int st = 0; st < 2; ++st) {
                const char* rp = (const char*)(AB8 + (size_t)rowc[st] * 256);
                const char* cp = (const char*)(AB8 + (size_t)colc[st] * 256 + 128);
                #pragma unroll
                for (int ks = 0; ks < 4; ++ks) {
                    va[st][ks] = *(const uint2*)(rp + ks * 32 + lg * 8);
                    vb[st][ks] = *(const uint2*)(cp + ks * 32 + lg * 8);
                }
            }
        } else {
            // ablation: synthesize from indices (rowc/colc stay live & consumed)
            #pragma unroll
            for (int st = 0; st < 2; ++st) {
                u32 r = (u32)rowc[st], c = (u32)colc[st];
                #pragma unroll
                for (int ks = 0; ks < 4; ++ks) {
                    va[st][ks] = make_uint2(r * 0x9E3779B9u + (u32)(ks * 0x85EB + lg), r ^ (u32)(ks + lg));
                    vb[st][ks] = make_uint2(c * 0xC2B2AE35u + (u32)ks, c + (u32)(lg * 3));
                }
            }
        }
        float emc[2], cdc[2];
        #pragma unroll
        for (int st = 0; st < 2; ++st) {
            emc[st] = edge_mask[min(e0 + st * 16 + le, E - 1)];
            cdc[st] = coord_diff[min(e0 * 3 + st * 48 + lane, E * 3 - 1)];
        }

        int next = tile + nwaves;
        bool hn = next < ntiles;
        int ne0 = (hn ? next : tile) << 5;
        int rown[2], coln[2];
        float ean[2];
        #pragma unroll
        for (int st = 0; st < 2; ++st) {
            int ep = min(ne0 + st * 16 + le, E - 1);
            rown[st] = eidx[ep]; coln[st] = eidx[E + ep]; ean[st] = edge_attr[ep];
        }

        i64 pa[2][4];
        #pragma unroll
        for (int st = 0; st < 2; ++st)
            #pragma unroll
            for (int ks = 0; ks < 4; ++ks)
                pa[st][ks] = conv_frag(va[st][ks], vb[st][ks], eac[st], ks, lg, vw1c);

        #pragma unroll
        for (int st = 0; st < 2; ++st) {
            float s[4] = { 0.f, 0.f, 0.f, 0.f };
            #pragma unroll
            for (int hf = 0; hf < 2; ++hf) {
                f32x4 acc[4] = {};
                #pragma unroll
                for (int ks = 0; ks < 4; ++ks) {
                    #pragma unroll
                    for (int nt = 0; nt < 4; ++nt) {
                        int row = (hf * 4 + nt) * 16 + le;
                        u64 b8 = *(const u64*)(w2s8 + row * 128 +
                                 (((ks * 32) + (lg * 8)) ^ ((le & 7) << 4)));
                        acc[nt] = __builtin_amdgcn_mfma_f32_16x16x32_fp8_fp8(pa[st][ks], (i64)b8, acc[nt], 0, 0, 0);
                    }
                }
                #pragma unroll
                for (int nt = 0; nt < 4; ++nt) {
                    int j = (hf * 4 + nt) * 16 + le;
                    float b2j = vb2[j];
                    float w3j = vw3[j];
                    #pragma unroll
                    for (int r = 0; r < 4; ++r)
                        s[r] += silu(acc[nt][r] + b2j) * w3j;
                }
            }
            #pragma unroll
            for (int r = 0; r < 4; ++r) {
                float t = s[r];
                t += __shfl_xor(t, 1);
                t += __shfl_xor(t, 2);
                t += __shfl_xor(t, 4);
                t += __shfl_xor(t, 8);
                s[r] = t;
            }
            if (le == 0) {
                f32x4 sv = { s[0], s[1], s[2], s[3] };
                *(f32x4*)&ssc[wv][st][lg * 4] = sv;
            }

            int els = (lane < 48) ? (lane / 3) : 0;
            int rA = __shfl(rowc[st], els);
            float emA = __shfl(emc[st], els);
            float sc = ssc[wv][st][els];
            int esub = e0 + st * 16 + els;
            if (lane < 48 && esub < E)
                atomicAdd(&agg[rA * 3 + (lane - els * 3)], cdc[st] * emA * sc);
        }

        if (!hn) break;
        tile = next; e0 = ne0;
        #pragma unroll
        for (int st = 0; st < 2; ++st) {
            rowc[st] = rown[st]; colc[st] = coln[st]; eac[st] = ean[st];
        }
    }
}

__global__ __launch_bounds__(256) void edge_kernel(
        const u8* __restrict__ AB8, const u8* __restrict__ W2T8,
        const int* __restrict__ eidx, const float* __restrict__ coord_diff,
        const float* __restrict__ edge_attr, const float* __restrict__ edge_mask,
        const float* __restrict__ W1, const float* __restrict__ b2,
        const float* __restrict__ W3, float* __restrict__ agg, int E) {
    edge_body<1>(AB8, W2T8, eidx, coord_diff, edge_attr, edge_mask, W1, b2, W3, agg, E);
}

// ablation probe: identical except NO AB8 gather; scatters to scratch buffer
__global__ __launch_bounds__(256) void edge_abl(
        const u8* __restrict__ AB8, const u8* __restrict__ W2T8,
        const int* __restrict__ eidx, const float* __restrict__ coord_diff,
        const float* __restrict__ edge_attr, const float* __restrict__ edge_mask,
        const float* __restrict__ W1, const float* __restrict__ b2,
        const float* __restrict__ W3, float* __restrict__ aggX, int E) {
    edge_body<0>(AB8, W2T8, eidx, coord_diff, edge_attr, edge_mask, W1, b2, W3, aggX, E);
}

// ---------------- kernel 3: coord update ----------------
__global__ void finalize(const float* __restrict__ coord, const float* __restrict__ agg,
                         const float* __restrict__ node_mask, float* __restrict__ out, int n3) {
    int i = blockIdx.x * blockDim.x + threadIdx.x;
    if (i < n3) {
        int n = i / 3;
        out[i] = (coord[i] + agg[i] * NORM_INV) * node_mask[n];
    }
}

extern "C" void kernel_launch(void* const* d_in, const int* in_sizes, int n_in,
                              void* d_out, int out_size, void* d_ws, size_t ws_size,
                              hipStream_t stream) {
    const float* h          = (const float*)d_in[0];
    const float* coord      = (const float*)d_in[1];
    const int*   eidx       = (const int*)d_in[2];
    const float* coord_diff = (const float*)d_in[3];
    const float* edge_attr  = (const float*)d_in[4];
    const float* node_mask  = (const float*)d_in[5];
    const float* edge_mask  = (const float*)d_in[6];
    const float* W1         = (const float*)d_in[7];
    const float* b1         = (const float*)d_in[8];
    const float* W2         = (const float*)d_in[9];
    const float* b2         = (const float*)d_in[10];
    const float* W3         = (const float*)d_in[11];

    int N = in_sizes[0] / 128;   // 50000
    int E = in_sizes[2] / 2;     // 800000

    char* ws = (char*)d_ws;
    size_t off = 0;
    u8*  AB8   = (u8*)(ws + off);  off += (size_t)N * 256; off = (off + 255) & ~(size_t)255;
    u16* W1abT = (u16*)(ws + off); off += 256 * 128 * sizeof(u16);
    u8*  W2T8  = (u8*)(ws + off);  off += 128 * 128; off = (off + 255) & ~(size_t)255;
    float* agg = (float*)(ws + off); off += (size_t)N * 3 * sizeof(float); off = (off + 255) & ~(size_t)255;
    float* aggX = (float*)(ws + off); off += (size_t)N * 3 * sizeof(float);

    hipMemsetAsync(agg, 0, (size_t)N * 3 * sizeof(float), stream);
    hipLaunchKernelGGL(prep_weights, dim3(192), dim3(256), 0, stream, W1, W2, W1abT, W2T8);
    hipLaunchKernelGGL(ab_kernel, dim3((N + 31) / 32), dim3(256), 0, stream, h, b1, W1abT, AB8, N);
    // ABLATION PROBE (writes scratch; timing-only, output-neutral)
    hipLaunchKernelGGL(edge_abl, dim3(2048), dim3(256), 0, stream,
                       AB8, W2T8, eidx, coord_diff, edge_attr, edge_mask, W1, b2, W3, aggX, E);
    // real kernel
    hipLaunchKernelGGL(edge_kernel, dim3(2048), dim3(256), 0, stream,
                       AB8, W2T8, eidx, coord_diff, edge_attr, edge_mask, W1, b2, W3, agg, E);
    int n3 = N * 3;
    hipLaunchKernelGGL(finalize, dim3((n3 + 255) / 256), dim3(256), 0, stream,
                       coord, agg, node_mask, (float*)d_out, n3);
}

// Round 14
// 117.606 us; speedup vs baseline: 3.4355x; 3.4355x over previous
//
#include <hip/hip_runtime.h>
#include <hip/hip_bf16.h>

typedef __attribute__((ext_vector_type(8))) short short8;
typedef __attribute__((ext_vector_type(4))) float f32x4;
typedef __attribute__((ext_vector_type(2))) float f32x2;
typedef unsigned short u16;
typedef unsigned int u32;
typedef unsigned char u8;
typedef unsigned long long u64;
typedef long long i64;

#define NORM_INV (1.0f / 100.0f)

__device__ __forceinline__ float silu(float x) {
    return x * __builtin_amdgcn_rcpf(1.0f + __expf(-x));
}

__device__ __forceinline__ u16 f2bf(float x) {
    union { float f; u32 u; } v; v.f = x;
    u32 r = v.u + 0x7fff + ((v.u >> 16) & 1);   // RNE
    return (u16)(r >> 16);
}

// ---------------- kernel 0: weight transposes (tiny) ----------------
__global__ void prep_weights(const float* __restrict__ W1, const float* __restrict__ W2,
                             u16* __restrict__ W1abT, u8* __restrict__ W2T8) {
    int idx = blockIdx.x * blockDim.x + threadIdx.x;
    if (idx < 256 * 128) {
        int j = idx >> 7, k = idx & 127;
        float v = (j < 128) ? W1[k * 128 + j] : W1[(128 + k) * 128 + (j - 128)];
        W1abT[j * 128 + k] = f2bf(v);
    } else if (idx < 256 * 128 + 128 * 128) {
        int t = idx - 256 * 128;
        int n = t >> 7, k = t & 127;
        float v = W2[k * 128 + n];
        int pk = __builtin_amdgcn_cvt_pk_fp8_f32(v, v, 0, false);
        W2T8[n * 128 + k] = (u8)pk;
    }
}

// ---------------- kernel 1: AB8[node][256] = fp8[h@W1a + b1 | h@W1b] ----------------
__global__ __launch_bounds__(256) void ab_kernel(const float* __restrict__ h,
        const float* __restrict__ b1, const u16* __restrict__ W1abT,
        u8* __restrict__ AB8, int N) {
    __shared__ u16 hs[32 * 128];     // 32 nodes x 128 k, bf16, XOR-swizzled
    int tid = threadIdx.x;
    int n0 = blockIdx.x * 32;
    int lane = tid & 63, wave = tid >> 6;

    #pragma unroll
    for (int it = 0; it < 8; ++it) {
        int item = it * 256 + tid;          // 2048 items, 2 k each
        int m = item >> 6;
        int k = (item & 63) * 2;
        float2 hv = make_float2(0.f, 0.f);
        if (n0 + m < N) hv = *(const float2*)(h + (size_t)(n0 + m) * 128 + k);
        u32 pk = (u32)f2bf(hv.x) | ((u32)f2bf(hv.y) << 16);
        int byteoff = m * 256 + ((k * 2) ^ ((m & 7) << 4));
        *(u32*)((char*)hs + byteoff) = pk;
    }

    short8 bw[4][4];
    #pragma unroll
    for (int nt = 0; nt < 4; ++nt) {
        int j = wave * 64 + nt * 16 + (lane & 15);
        #pragma unroll
        for (int ks = 0; ks < 4; ++ks)
            bw[nt][ks] = *(const short8*)((const char*)W1abT + j * 256 + ks * 64 + (lane >> 4) * 16);
    }
    __syncthreads();

    f32x4 acc[2][4] = {};
    #pragma unroll
    for (int ks = 0; ks < 4; ++ks) {
        short8 a[2];
        #pragma unroll
        for (int mt = 0; mt < 2; ++mt) {
            int row = mt * 16 + (lane & 15);
            int byteoff = row * 256 + (((ks * 64) + ((lane >> 4) * 16)) ^ ((row & 7) << 4));
            a[mt] = *(short8*)((char*)hs + byteoff);
        }
        #pragma unroll
        for (int mt = 0; mt < 2; ++mt)
            #pragma unroll
            for (int nt = 0; nt < 4; ++nt)
                acc[mt][nt] = __builtin_amdgcn_mfma_f32_16x16x32_bf16(a[mt], bw[nt][ks], acc[mt][nt], 0, 0, 0);
    }

    #pragma unroll
    for (int mt = 0; mt < 2; ++mt) {
        #pragma unroll
        for (int nt = 0; nt < 4; ++nt) {
            int j = wave * 64 + nt * 16 + (lane & 15);
            float bias = (j < 128) ? b1[j] : 0.f;
            #pragma unroll
            for (int r = 0; r < 4; ++r) {
                int node = n0 + mt * 16 + (lane >> 4) * 4 + r;
                if (node < N) {
                    float v = acc[mt][nt][r] + bias;
                    int pk = __builtin_amdgcn_cvt_pk_fp8_f32(v, v, 0, false);
                    AB8[(size_t)node * 256 + j] = (u8)pk;
                }
            }
        }
    }
}

// fp8 gather pair + layer-1 finish + silu -> fp8 A-fragment (constants in regs)
__device__ __forceinline__ i64 conv_frag(uint2 va, uint2 vb, float eac, float4 w0, float4 w1) {
    f32x2 fa[4], fb[4];
    fa[0] = __builtin_amdgcn_cvt_pk_f32_fp8(va.x, false);
    fa[1] = __builtin_amdgcn_cvt_pk_f32_fp8(va.x, true);
    fa[2] = __builtin_amdgcn_cvt_pk_f32_fp8(va.y, false);
    fa[3] = __builtin_amdgcn_cvt_pk_f32_fp8(va.y, true);
    fb[0] = __builtin_amdgcn_cvt_pk_f32_fp8(vb.x, false);
    fb[1] = __builtin_amdgcn_cvt_pk_f32_fp8(vb.x, true);
    fb[2] = __builtin_amdgcn_cvt_pk_f32_fp8(vb.y, false);
    fb[3] = __builtin_amdgcn_cvt_pk_f32_fp8(vb.y, true);
    const float wc[8] = { w0.x, w0.y, w0.z, w0.w, w1.x, w1.y, w1.z, w1.w };
    float x[8];
    #pragma unroll
    for (int jp = 0; jp < 4; ++jp) {
        x[2 * jp]     = silu(fa[jp].x + fb[jp].x + eac * wc[2 * jp]);
        x[2 * jp + 1] = silu(fa[jp].y + fb[jp].y + eac * wc[2 * jp + 1]);
    }
    u32 lo = 0, hi = 0;
    lo = __builtin_amdgcn_cvt_pk_fp8_f32(x[0], x[1], lo, false);
    lo = __builtin_amdgcn_cvt_pk_fp8_f32(x[2], x[3], lo, true);
    hi = __builtin_amdgcn_cvt_pk_fp8_f32(x[4], x[5], hi, false);
    hi = __builtin_amdgcn_cvt_pk_fp8_f32(x[6], x[7], hi, true);
    union { uint2 u; i64 l; } c; c.u = make_uint2(lo, hi);
    return c.l;
}

// ---------------- kernel 2: wave-autonomous edge MLP + scatter ----------------
// r14: NO volatile (r13 ablation: body-without-gather ~175us -- the 96 serialized
// scalar volatile LDS reads/tile were the cost, not the gather). Constants are
// re-loaded per tile as 12 WIDE LDS loads whose addresses are laundered through
// an empty asm (blocks LICM -> no loop-carried register bloat) and whose live
// ranges are split: w1c dies after convert, b2w3 lives only in the epilogue.
__global__ __launch_bounds__(256) void edge_kernel(
        const u8* __restrict__ AB8, const u8* __restrict__ W2T8,
        const int* __restrict__ eidx, const float* __restrict__ coord_diff,
        const float* __restrict__ edge_attr, const float* __restrict__ edge_mask,
        const float* __restrict__ W1, const float* __restrict__ b2,
        const float* __restrict__ W3, float* __restrict__ agg, int E) {
    __shared__ u8 w2s8[128 * 128];   // swizzled fp8 W2T copy (16 KB)
    __shared__ float ssc[4][16];     // per-wave scale scratch
    __shared__ float sw1c[128];      // W1 edge_attr row
    __shared__ float2 sb2w3[128];    // interleaved (b2[j], W3[j])

    const int tid = threadIdx.x;
    const int lane = tid & 63;
    const int wv = tid >> 6;
    const int le = lane & 15;        // edge-sub / col-sub
    const int lg = lane >> 4;        // k-chunk group 0..3

    #pragma unroll
    for (int it = 0; it < 8; ++it) {
        int idx = it * 256 + tid;
        int row = idx >> 4, c8 = idx & 15;
        u64 v = *(const u64*)(W2T8 + row * 128 + c8 * 8);
        *(u64*)(w2s8 + row * 128 + ((c8 * 8) ^ ((row & 7) << 4))) = v;
    }
    if (tid < 128) {
        sw1c[tid] = W1[256 * 128 + tid];
        sb2w3[tid] = make_float2(b2[tid], W3[tid]);
    }
    __syncthreads();                  // only barrier in kernel

    const int ntiles = (E + 15) >> 4;
    const int wpb = blockDim.x >> 6;
    const int nwaves = gridDim.x * wpb;
    int tile = blockIdx.x * wpb + wv;
    if (tile >= ntiles) return;

    // ---- prologue: meta(t0)
    int e0 = tile << 4;
    int ep = min(e0 + le, E - 1);
    int rowc = eidx[ep];
    int colc = eidx[E + ep];
    float eac = edge_attr[ep];

    while (true) {
        // issue gather(cur) from prefetched meta (1-hop chain)
        uint2 va[4], vb[4];
        {
            const char* rp = (const char*)(AB8 + (size_t)rowc * 256);
            const char* cp = (const char*)(AB8 + (size_t)colc * 256 + 128);
            #pragma unroll
            for (int ks = 0; ks < 4; ++ks) {
                va[ks] = *(const uint2*)(rp + ks * 32 + lg * 8);
                vb[ks] = *(const uint2*)(cp + ks * 32 + lg * 8);
            }
        }
        float eml = edge_mask[min(e0 + le, E - 1)];
        float cdl = coord_diff[min(e0 * 3 + lane, E * 3 - 1)];

        // issue meta(next) (breaks next tile's 2-hop chain)
        int next = tile + nwaves;
        bool hn = next < ntiles;
        int ne0 = (hn ? next : tile) << 4;
        int nep = min(ne0 + le, E - 1);
        int rown = eidx[nep];
        int coln = eidx[E + nep];
        float ean = edge_attr[nep];

        // w1c: 8 wide LDS loads, address laundered (no LICM), batched wait.
        int z0 = 0;
        asm volatile("" : "+v"(z0));
        float4 wq[8];
        #pragma unroll
        for (int ks = 0; ks < 4; ++ks) {
            wq[2 * ks]     = *(const float4*)&sw1c[z0 + ks * 32 + lg * 8];
            wq[2 * ks + 1] = *(const float4*)&sw1c[z0 + ks * 32 + lg * 8 + 4];
        }

        // convert (w1c regs die here)
        i64 pa[4];
        #pragma unroll
        for (int ks = 0; ks < 4; ++ks)
            pa[ks] = conv_frag(va[ks], vb[ks], eac, wq[2 * ks], wq[2 * ks + 1]);

        // layer 2 fp8 MFMA in two n-halves + epilogue (b2w3 loaded here only)
        int z1 = 0;
        asm volatile("" : "+v"(z1));
        float s[4] = { 0.f, 0.f, 0.f, 0.f };
        #pragma unroll
        for (int hf = 0; hf < 2; ++hf) {
            f32x4 acc[4] = {};
            #pragma unroll
            for (int ks = 0; ks < 4; ++ks) {
                #pragma unroll
                for (int nt = 0; nt < 4; ++nt) {
                    int row = (hf * 4 + nt) * 16 + le;
                    u64 b8 = *(const u64*)(w2s8 + row * 128 +
                             (((ks * 32) + (lg * 8)) ^ ((le & 7) << 4)));
                    acc[nt] = __builtin_amdgcn_mfma_f32_16x16x32_fp8_fp8(pa[ks], (i64)b8, acc[nt], 0, 0, 0);
                }
            }
            float2 bw[4];
            #pragma unroll
            for (int nt = 0; nt < 4; ++nt)
                bw[nt] = sb2w3[z1 + (hf * 4 + nt) * 16 + le];
            #pragma unroll
            for (int nt = 0; nt < 4; ++nt) {
                #pragma unroll
                for (int r = 0; r < 4; ++r)
                    s[r] += silu(acc[nt][r] + bw[nt].x) * bw[nt].y;
            }
        }
        #pragma unroll
        for (int r = 0; r < 4; ++r) {
            float t = s[r];
            t += __shfl_xor(t, 1);
            t += __shfl_xor(t, 2);
            t += __shfl_xor(t, 4);
            t += __shfl_xor(t, 8);
            s[r] = t;                 // edge lg*4+r, valid at le==0
        }
        if (le == 0) {
            f32x4 sv = { s[0], s[1], s[2], s[3] };
            *(f32x4*)&ssc[wv][lg * 4] = sv;   // same-wave LDS, lgkmcnt-ordered
        }

        // scatter: 3 atomics per edge (lanes 0..47)
        int els = (lane < 48) ? (lane / 3) : 0;
        int rA = __shfl(rowc, els);
        float emA = __shfl(eml, els);
        float sc = ssc[wv][els];
        if (lane < 48 && (e0 + els) < E)
            atomicAdd(&agg[rA * 3 + (lane - els * 3)], cdl * emA * sc);

        if (!hn) break;
        tile = next; e0 = ne0;
        rowc = rown; colc = coln; eac = ean;
    }
}

// ---------------- kernel 3: coord update ----------------
__global__ void finalize(const float* __restrict__ coord, const float* __restrict__ agg,
                         const float* __restrict__ node_mask, float* __restrict__ out, int n3) {
    int i = blockIdx.x * blockDim.x + threadIdx.x;
    if (i < n3) {
        int n = i / 3;
        out[i] = (coord[i] + agg[i] * NORM_INV) * node_mask[n];
    }
}

extern "C" void kernel_launch(void* const* d_in, const int* in_sizes, int n_in,
                              void* d_out, int out_size, void* d_ws, size_t ws_size,
                              hipStream_t stream) {
    const float* h          = (const float*)d_in[0];
    const float* coord      = (const float*)d_in[1];
    const int*   eidx       = (const int*)d_in[2];
    const float* coord_diff = (const float*)d_in[3];
    const float* edge_attr  = (const float*)d_in[4];
    const float* node_mask  = (const float*)d_in[5];
    const float* edge_mask  = (const float*)d_in[6];
    const float* W1         = (const float*)d_in[7];
    const float* b1         = (const float*)d_in[8];
    const float* W2         = (const float*)d_in[9];
    const float* b2         = (const float*)d_in[10];
    const float* W3         = (const float*)d_in[11];

    int N = in_sizes[0] / 128;   // 50000
    int E = in_sizes[2] / 2;     // 800000

    char* ws = (char*)d_ws;
    size_t off = 0;
    u8*  AB8   = (u8*)(ws + off);  off += (size_t)N * 256; off = (off + 255) & ~(size_t)255;
    u16* W1abT = (u16*)(ws + off); off += 256 * 128 * sizeof(u16);
    u8*  W2T8  = (u8*)(ws + off);  off += 128 * 128; off = (off + 255) & ~(size_t)255;
    float* agg = (float*)(ws + off); off += (size_t)N * 3 * sizeof(float);

    hipMemsetAsync(agg, 0, (size_t)N * 3 * sizeof(float), stream);
    hipLaunchKernelGGL(prep_weights, dim3(192), dim3(256), 0, stream, W1, W2, W1abT, W2T8);
    hipLaunchKernelGGL(ab_kernel, dim3((N + 31) / 32), dim3(256), 0, stream, h, b1, W1abT, AB8, N);
    hipLaunchKernelGGL(edge_kernel, dim3(2048), dim3(256), 0, stream,
                       AB8, W2T8, eidx, coord_diff, edge_attr, edge_mask, W1, b2, W3, agg, E);
    int n3 = N * 3;
    hipLaunchKernelGGL(finalize, dim3((n3 + 255) / 256), dim3(256), 0, stream,
                       coord, agg, node_mask, (float*)d_out, n3);
}